// Round 2
// baseline (628.896 us; speedup 1.0000x reference)
//
#include <hip/hip_runtime.h>

// Laguerre FilterbankCell: y_t = M y_{t-1} + v x_t (K=12 state), output = state each step.
// Chunked parallel linear scan. One thread owns BOTH groups of one b:
//   x loads  -> one float4 per 2 steps (fully used 16 B/lane)
//   out stores -> 96 B contiguous per lane per step (per-lane streaming, L2 merges lines)

#define KF 12
#define GF 2
#define BF 2048
#define SF 2048
#define BG (BF * GF)      // 4096

// ---------------------------------------------------------------------------
// One recurrence step for both groups, interleaved for ILP.
// ---------------------------------------------------------------------------
__device__ __forceinline__ void fb_step2(float* __restrict__ y0, float* __restrict__ y1,
                                         float x0, float x1,
                                         float sa0, float tsb0, float sa1, float tsb1) {
    float pm0 = y0[0], pm1 = y1[0];
    y0[0] = fmaf(sa0, y0[0], tsb0 * x0);
    y1[0] = fmaf(sa1, y1[0], tsb1 * x1);
    #pragma unroll
    for (int j = 1; j < KF; ++j) {
        const float t0 = y0[j], t1 = y1[j];
        y0[j] = fmaf(sa0, t0, fmaf(sa0, y0[j - 1], -pm0));
        y1[j] = fmaf(sa1, t1, fmaf(sa1, y1[j - 1], -pm1));
        pm0 = t0; pm1 = t1;
    }
}

// ---------------------------------------------------------------------------
// Setup: Mp[g] = M^(SF/NC) via log2 repeated squarings in LDS.
// M[j][j]=sa; M[j][m] = -(1-sa^2)*sa^(j-m-1) for m<j.
// ---------------------------------------------------------------------------
template <int NC>
__global__ void setup_mpow(const float* __restrict__ relax, float* __restrict__ Mp) {
    constexpr int LCH = SF / NC;
    constexpr int LOG2L = (LCH == 16) ? 4 : ((LCH == 32) ? 5 : 6);
    const int g = blockIdx.x;
    const int t = threadIdx.x;
    __shared__ float A[KF][KF];
    const float rx = relax[g];
    const float sa = sqrtf(rx);

    if (t < KF * KF) {
        const int j = t / KF, m = t % KF;
        float v = 0.0f;
        if (m == j) {
            v = sa;
        } else if (m < j) {
            float p = 1.0f;
            for (int i = 0; i < j - m - 1; ++i) p *= sa;
            v = -(1.0f - rx) * p;
        }
        A[j][m] = v;
    }
    __syncthreads();

    for (int it = 0; it < LOG2L; ++it) {
        float s = 0.0f;
        if (t < KF * KF) {
            const int j = t / KF, m = t % KF;
            #pragma unroll
            for (int i = 0; i < KF; ++i) s += A[j][i] * A[i][m];
        }
        __syncthreads();
        if (t < KF * KF) A[t / KF][t % KF] = s;
        __syncthreads();
    }

    if (t < KF * KF) Mp[g * KF * KF + t] = A[t / KF][t % KF];
}

// ---------------------------------------------------------------------------
// Pass 1: thread (b,c) runs chunk c from zero state for both groups;
// stores end states (24 floats contiguous) at F[(c*BF+b)*24].
// Lane mapping: c = tid & (NC-1)  (adjacent lanes -> adjacent chunks, same b).
// ---------------------------------------------------------------------------
template <int NC>
__global__ __launch_bounds__(256, 4) void pass1_chunk_states(
        const float* __restrict__ x, const float* __restrict__ relax,
        float* __restrict__ F) {
    constexpr int LCH = SF / NC;
    const int tid = blockIdx.x * 256 + threadIdx.x;
    const int c = tid & (NC - 1);
    const int b = tid / NC;

    const float r0 = relax[0], r1 = relax[1];
    const float sa0 = sqrtf(r0), tsb0 = sqrtf(1.0f - r0);
    const float sa1 = sqrtf(r1), tsb1 = sqrtf(1.0f - r1);

    float y0[KF], y1[KF];
    #pragma unroll
    for (int k = 0; k < KF; ++k) { y0[k] = 0.0f; y1[k] = 0.0f; }

    const float4* xp = (const float4*)(x + ((size_t)b * SF + (size_t)c * LCH) * GF);
    #pragma unroll 2
    for (int t2 = 0; t2 < LCH / 2; ++t2) {
        const float4 xv = xp[t2];
        fb_step2(y0, y1, xv.x, xv.y, sa0, tsb0, sa1, tsb1);
        fb_step2(y0, y1, xv.z, xv.w, sa0, tsb0, sa1, tsb1);
    }

    float4* Fp = (float4*)(F + ((size_t)c * BF + b) * (GF * KF));
    Fp[0] = make_float4(y0[0], y0[1], y0[2],  y0[3]);
    Fp[1] = make_float4(y0[4], y0[5], y0[6],  y0[7]);
    Fp[2] = make_float4(y0[8], y0[9], y0[10], y0[11]);
    Fp[3] = make_float4(y1[0], y1[1], y1[2],  y1[3]);
    Fp[4] = make_float4(y1[4], y1[5], y1[6],  y1[7]);
    Fp[5] = make_float4(y1[8], y1[9], y1[10], y1[11]);
}

// ---------------------------------------------------------------------------
// Pass 2: per (b,g): s_in(c) = Mp*s_in(c-1) + F(c-1), stored into slot c-1.
// 16 lanes per (b,g); lane sub<12 owns component k; matvec via __shfl.
// ---------------------------------------------------------------------------
template <int NC>
__global__ void pass2_combine(float* __restrict__ F, const float* __restrict__ Mp) {
    const int tid = blockIdx.x * blockDim.x + threadIdx.x;   // BG*16 threads
    const int sub = tid & 15;
    const int bg  = tid >> 4;          // [0, BG) ; bg = b*2+g
    const int g   = bg & 1;
    const int lane = threadIdx.x & 63;
    const int grpbase = lane & ~15;

    const int k = (sub < KF) ? sub : 0;
    float Mrow[KF];
    const float* mr = Mp + ((size_t)g * KF + k) * KF;
    #pragma unroll
    for (int m = 0; m < KF; ++m) Mrow[m] = mr[m];

    float r = 0.0f;
    for (int c = 1; c < NC; ++c) {
        float* slot = F + ((size_t)(c - 1) * BG + bg) * KF + k;
        float acc = *slot;
        #pragma unroll
        for (int m = 0; m < KF; ++m) {
            acc += Mrow[m] * __shfl(r, grpbase + m, 64);
        }
        if (sub < KF) *slot = acc;
        r = acc;
    }
}

// ---------------------------------------------------------------------------
// Pass 3: thread (b,c) loads s_in (slot c-1; zeros for c==0), re-runs chunk,
// streams 96 B contiguous per step.
// ---------------------------------------------------------------------------
template <int NC>
__global__ __launch_bounds__(256, 4) void pass3_outputs(
        const float* __restrict__ x, const float* __restrict__ relax,
        const float* __restrict__ F, float* __restrict__ out) {
    constexpr int LCH = SF / NC;
    const int tid = blockIdx.x * 256 + threadIdx.x;
    const int c = tid & (NC - 1);
    const int b = tid / NC;

    const float r0 = relax[0], r1 = relax[1];
    const float sa0 = sqrtf(r0), tsb0 = sqrtf(1.0f - r0);
    const float sa1 = sqrtf(r1), tsb1 = sqrtf(1.0f - r1);

    float y0[KF], y1[KF];
    if (c == 0) {
        #pragma unroll
        for (int k = 0; k < KF; ++k) { y0[k] = 0.0f; y1[k] = 0.0f; }
    } else {
        const float4* Fp = (const float4*)(F + ((size_t)(c - 1) * BF + b) * (GF * KF));
        const float4 a0 = Fp[0], a1 = Fp[1], a2 = Fp[2];
        const float4 a3 = Fp[3], a4 = Fp[4], a5 = Fp[5];
        y0[0] = a0.x; y0[1] = a0.y; y0[2]  = a0.z; y0[3]  = a0.w;
        y0[4] = a1.x; y0[5] = a1.y; y0[6]  = a1.z; y0[7]  = a1.w;
        y0[8] = a2.x; y0[9] = a2.y; y0[10] = a2.z; y0[11] = a2.w;
        y1[0] = a3.x; y1[1] = a3.y; y1[2]  = a3.z; y1[3]  = a3.w;
        y1[4] = a4.x; y1[5] = a4.y; y1[6]  = a4.z; y1[7]  = a4.w;
        y1[8] = a5.x; y1[9] = a5.y; y1[10] = a5.z; y1[11] = a5.w;
    }

    const float4* xp = (const float4*)(x + ((size_t)b * SF + (size_t)c * LCH) * GF);
    float* op = out + ((size_t)b * SF + (size_t)c * LCH) * (GF * KF);

    #pragma unroll 2
    for (int t2 = 0; t2 < LCH / 2; ++t2) {
        const float4 xv = xp[t2];

        fb_step2(y0, y1, xv.x, xv.y, sa0, tsb0, sa1, tsb1);
        float4* o4 = (float4*)(op + (size_t)(2 * t2) * (GF * KF));
        o4[0] = make_float4(y0[0], y0[1], y0[2],  y0[3]);
        o4[1] = make_float4(y0[4], y0[5], y0[6],  y0[7]);
        o4[2] = make_float4(y0[8], y0[9], y0[10], y0[11]);
        o4[3] = make_float4(y1[0], y1[1], y1[2],  y1[3]);
        o4[4] = make_float4(y1[4], y1[5], y1[6],  y1[7]);
        o4[5] = make_float4(y1[8], y1[9], y1[10], y1[11]);

        fb_step2(y0, y1, xv.z, xv.w, sa0, tsb0, sa1, tsb1);
        float4* o4b = (float4*)(op + (size_t)(2 * t2 + 1) * (GF * KF));
        o4b[0] = make_float4(y0[0], y0[1], y0[2],  y0[3]);
        o4b[1] = make_float4(y0[4], y0[5], y0[6],  y0[7]);
        o4b[2] = make_float4(y0[8], y0[9], y0[10], y0[11]);
        o4b[3] = make_float4(y1[0], y1[1], y1[2],  y1[3]);
        o4b[4] = make_float4(y1[4], y1[5], y1[6],  y1[7]);
        o4b[5] = make_float4(y1[8], y1[9], y1[10], y1[11]);
    }
}

// ---------------------------------------------------------------------------
template <int NC>
static void run_all(const float* x, const float* relax, float* out,
                    float* Mp, float* F, hipStream_t stream) {
    setup_mpow<NC><<<GF, 192, 0, stream>>>(relax, Mp);
    const int threads13 = BF * NC;
    pass1_chunk_states<NC><<<threads13 / 256, 256, 0, stream>>>(x, relax, F);
    pass2_combine<NC><<<(BG * 16) / 256, 256, 0, stream>>>(F, Mp);
    pass3_outputs<NC><<<threads13 / 256, 256, 0, stream>>>(x, relax, F, out);
}

extern "C" void kernel_launch(void* const* d_in, const int* in_sizes, int n_in,
                              void* d_out, int out_size, void* d_ws, size_t ws_size,
                              hipStream_t stream) {
    const float* x     = (const float*)d_in[0];   // [B,S,G] f32
    const float* relax = (const float*)d_in[1];   // [G] f32
    float* out = (float*)d_out;                   // [B,S,G,K] f32

    float* Mp = (float*)d_ws;                     // G*K*K floats
    float* F  = (float*)((char*)d_ws + 4096);     // NC*BF*24 floats

    const size_t need128 = 4096 + (size_t)128 * BF * (GF * KF) * sizeof(float); // ~25 MB
    if (ws_size >= need128) {
        run_all<128>(x, relax, out, Mp, F, stream);
    } else {
        run_all<64>(x, relax, out, Mp, F, stream);
    }
}

// Round 3
// 534.737 us; speedup vs baseline: 1.1761x; 1.1761x over previous
//
#include <hip/hip_runtime.h>

// Laguerre FilterbankCell via chunked parallel linear scan.
// Key change vs prev round: pass3 stages 2 steps/lane in wave-private LDS and
// flushes cooperatively (12 lanes per 192-B record) so each store instruction
// touches ~22 cache lines instead of 64 -> ~3x fewer write transactions.

#define KF 12
#define GF 2
#define BF 2048
#define SF 2048
#define BG (BF * GF)
#define PSTR 52            // per-lane LDS stride in floats (2*24 + 4 pad)

// ---------------------------------------------------------------------------
__device__ __forceinline__ void fb_step2(float* __restrict__ y0, float* __restrict__ y1,
                                         float x0, float x1,
                                         float sa0, float tsb0, float sa1, float tsb1) {
    float pm0 = y0[0], pm1 = y1[0];
    y0[0] = fmaf(sa0, y0[0], tsb0 * x0);
    y1[0] = fmaf(sa1, y1[0], tsb1 * x1);
    #pragma unroll
    for (int j = 1; j < KF; ++j) {
        const float t0 = y0[j], t1 = y1[j];
        y0[j] = fmaf(sa0, t0, fmaf(sa0, y0[j - 1], -pm0));
        y1[j] = fmaf(sa1, t1, fmaf(sa1, y1[j - 1], -pm1));
        pm0 = t0; pm1 = t1;
    }
}

// ---------------------------------------------------------------------------
// Setup: Mp[g] = M^(SF/NC) via repeated squaring in LDS.
// ---------------------------------------------------------------------------
template <int NC>
__global__ void setup_mpow(const float* __restrict__ relax, float* __restrict__ Mp) {
    constexpr int LCH = SF / NC;
    constexpr int LOG2L = (LCH == 16) ? 4 : ((LCH == 32) ? 5 : 6);
    const int g = blockIdx.x;
    const int t = threadIdx.x;
    __shared__ float A[KF][KF];
    const float rx = relax[g];
    const float sa = sqrtf(rx);

    if (t < KF * KF) {
        const int j = t / KF, m = t % KF;
        float v = 0.0f;
        if (m == j) {
            v = sa;
        } else if (m < j) {
            float p = 1.0f;
            for (int i = 0; i < j - m - 1; ++i) p *= sa;
            v = -(1.0f - rx) * p;
        }
        A[j][m] = v;
    }
    __syncthreads();

    for (int it = 0; it < LOG2L; ++it) {
        float s = 0.0f;
        if (t < KF * KF) {
            const int j = t / KF, m = t % KF;
            #pragma unroll
            for (int i = 0; i < KF; ++i) s += A[j][i] * A[i][m];
        }
        __syncthreads();
        if (t < KF * KF) A[t / KF][t % KF] = s;
        __syncthreads();
    }

    if (t < KF * KF) Mp[g * KF * KF + t] = A[t / KF][t % KF];
}

// ---------------------------------------------------------------------------
// Pass 1: thread (b,c) runs chunk c from zero; stores 24-float end state at
// F[(b*NC + c)*24]  (records contiguous across lanes -> compact 6 KB span).
// ---------------------------------------------------------------------------
template <int NC>
__global__ __launch_bounds__(256, 4) void pass1_chunk_states(
        const float* __restrict__ x, const float* __restrict__ relax,
        float* __restrict__ F) {
    constexpr int LCH = SF / NC;
    const int tid = blockIdx.x * 256 + threadIdx.x;
    const int c = tid & (NC - 1);
    const int b = tid / NC;

    const float r0 = relax[0], r1 = relax[1];
    const float sa0 = sqrtf(r0), tsb0 = sqrtf(1.0f - r0);
    const float sa1 = sqrtf(r1), tsb1 = sqrtf(1.0f - r1);

    float y0[KF], y1[KF];
    #pragma unroll
    for (int k = 0; k < KF; ++k) { y0[k] = 0.0f; y1[k] = 0.0f; }

    const float4* xp = (const float4*)(x + ((size_t)b * SF + (size_t)c * LCH) * GF);
    for (int t2 = 0; t2 < LCH / 2; ++t2) {
        const float4 xv = xp[t2];
        fb_step2(y0, y1, xv.x, xv.y, sa0, tsb0, sa1, tsb1);
        fb_step2(y0, y1, xv.z, xv.w, sa0, tsb0, sa1, tsb1);
    }

    float4* Fp = (float4*)(F + ((size_t)b * NC + c) * (GF * KF));
    Fp[0] = make_float4(y0[0], y0[1], y0[2],  y0[3]);
    Fp[1] = make_float4(y0[4], y0[5], y0[6],  y0[7]);
    Fp[2] = make_float4(y0[8], y0[9], y0[10], y0[11]);
    Fp[3] = make_float4(y1[0], y1[1], y1[2],  y1[3]);
    Fp[4] = make_float4(y1[4], y1[5], y1[6],  y1[7]);
    Fp[5] = make_float4(y1[8], y1[9], y1[10], y1[11]);
}

// ---------------------------------------------------------------------------
// Pass 2: per (b,g): s_in(c) = Mp*s_in(c-1) + F(c-1), stored into slot c-1.
// 16 lanes per (b,g); one-slot prefetch hides load latency under the shuffle
// chain.
// ---------------------------------------------------------------------------
template <int NC>
__global__ void pass2_combine(float* __restrict__ F, const float* __restrict__ Mp) {
    const int tid = blockIdx.x * blockDim.x + threadIdx.x;   // BG*16 threads
    const int sub = tid & 15;
    const int bg  = tid >> 4;          // b*2+g
    const int b   = bg >> 1;
    const int g   = bg & 1;
    const int lane = threadIdx.x & 63;
    const int grpbase = lane & ~15;

    const int k = (sub < KF) ? sub : 0;
    float Mrow[KF];
    const float* mr = Mp + ((size_t)g * KF + k) * KF;
    #pragma unroll
    for (int m = 0; m < KF; ++m) Mrow[m] = mr[m];

    float* Fb = F + ((size_t)b * NC) * (GF * KF) + g * KF + k;

    float r = 0.0f;
    float fnext = Fb[0];                       // slot c-1 = 0 for c=1
    for (int c = 1; c < NC; ++c) {
        const float fcur = fnext;
        if (c + 1 < NC) fnext = Fb[(size_t)c * (GF * KF)];   // prefetch slot c
        float acc = fcur;
        #pragma unroll
        for (int m = 0; m < KF; ++m) {
            acc += Mrow[m] * __shfl(r, grpbase + m, 64);
        }
        if (sub < KF) Fb[(size_t)(c - 1) * (GF * KF)] = acc;
        r = acc;
    }
}

// ---------------------------------------------------------------------------
// Pass 3: wave owns 64 consecutive chunks of one b. Every 2 steps: stage
// 2x24 floats/lane in wave-private LDS, then flush cooperatively with 12
// lanes per 192-B record (contiguous), precomputed addresses.
// ---------------------------------------------------------------------------
template <int NC>
__global__ __launch_bounds__(256, 3) void pass3_outputs(
        const float* __restrict__ x, const float* __restrict__ relax,
        const float* __restrict__ F, float* __restrict__ out) {
    constexpr int LCH = SF / NC;
    constexpr int WPB = NC / 64;               // waves per b
    __shared__ __align__(16) float lds[4 * 64 * PSTR];

    const int lane = threadIdx.x & 63;
    const int w    = threadIdx.x >> 6;
    const int W    = blockIdx.x * 4 + w;       // global wave id
    const int b    = W / WPB;
    const int c0   = (W % WPB) * 64;
    const int c    = c0 + lane;

    const float r0 = relax[0], r1 = relax[1];
    const float sa0 = sqrtf(r0), tsb0 = sqrtf(1.0f - r0);
    const float sa1 = sqrtf(r1), tsb1 = sqrtf(1.0f - r1);

    float y0[KF], y1[KF];
    if (c == 0) {
        #pragma unroll
        for (int k = 0; k < KF; ++k) { y0[k] = 0.0f; y1[k] = 0.0f; }
    } else {
        const float4* Fp = (const float4*)(F + ((size_t)b * NC + (c - 1)) * (GF * KF));
        const float4 a0 = Fp[0], a1 = Fp[1], a2 = Fp[2];
        const float4 a3 = Fp[3], a4 = Fp[4], a5 = Fp[5];
        y0[0] = a0.x; y0[1] = a0.y; y0[2]  = a0.z; y0[3]  = a0.w;
        y0[4] = a1.x; y0[5] = a1.y; y0[6]  = a1.z; y0[7]  = a1.w;
        y0[8] = a2.x; y0[9] = a2.y; y0[10] = a2.z; y0[11] = a2.w;
        y1[0] = a3.x; y1[1] = a3.y; y1[2]  = a3.z; y1[3]  = a3.w;
        y1[4] = a4.x; y1[5] = a4.y; y1[6]  = a4.z; y1[7]  = a4.w;
        y1[8] = a5.x; y1[9] = a5.y; y1[10] = a5.z; y1[11] = a5.w;
    }

    const float4* xp = (const float4*)(x + ((size_t)b * SF + (size_t)c * LCH) * GF);

    float* Lw  = lds + (size_t)w * 64 * PSTR;
    float* Lme = Lw + lane * PSTR;

    // Precompute flush addresses: v = j*64+lane; pair p = v/12 (record),
    // f4-within-record f = v%12. Record pair p = chunk c0+p, steps (t0,t0+1):
    // 192 B contiguous in global.
    const float4* Lrd[12];
    int goff[12];                               // f4 offset within b row (t0 part added per flush)
    #pragma unroll
    for (int j = 0; j < 12; ++j) {
        const int v = j * 64 + lane;
        const int p = v / 12;
        const int f = v - p * 12;
        Lrd[j]  = (const float4*)(Lw + p * PSTR + f * 4);
        goff[j] = (c0 + p) * (LCH * 6) + f;
    }
    float4* outb = (float4*)(out + (size_t)b * SF * (GF * KF));

    for (int i = 0; i < LCH / 2; ++i) {
        const float4 xv = xp[i];

        fb_step2(y0, y1, xv.x, xv.y, sa0, tsb0, sa1, tsb1);
        float4* Ls = (float4*)Lme;
        Ls[0] = make_float4(y0[0], y0[1], y0[2],  y0[3]);
        Ls[1] = make_float4(y0[4], y0[5], y0[6],  y0[7]);
        Ls[2] = make_float4(y0[8], y0[9], y0[10], y0[11]);
        Ls[3] = make_float4(y1[0], y1[1], y1[2],  y1[3]);
        Ls[4] = make_float4(y1[4], y1[5], y1[6],  y1[7]);
        Ls[5] = make_float4(y1[8], y1[9], y1[10], y1[11]);

        fb_step2(y0, y1, xv.z, xv.w, sa0, tsb0, sa1, tsb1);
        Ls[6]  = make_float4(y0[0], y0[1], y0[2],  y0[3]);
        Ls[7]  = make_float4(y0[4], y0[5], y0[6],  y0[7]);
        Ls[8]  = make_float4(y0[8], y0[9], y0[10], y0[11]);
        Ls[9]  = make_float4(y1[0], y1[1], y1[2],  y1[3]);
        Ls[10] = make_float4(y1[4], y1[5], y1[6],  y1[7]);
        Ls[11] = make_float4(y1[8], y1[9], y1[10], y1[11]);

        // wave-private: LDS ops are in-order within a wave; compiler keeps
        // program order on the same shared array (can't disprove aliasing).
        const int tbase = 12 * i;               // t0*6 in f4 units
        #pragma unroll
        for (int j = 0; j < 12; ++j) {
            outb[(size_t)(goff[j] + tbase)] = *Lrd[j];
        }
    }
}

// ---------------------------------------------------------------------------
template <int NC>
static void run_all(const float* x, const float* relax, float* out,
                    float* Mp, float* F, hipStream_t stream) {
    setup_mpow<NC><<<GF, 192, 0, stream>>>(relax, Mp);
    const int threads13 = BF * NC;
    pass1_chunk_states<NC><<<threads13 / 256, 256, 0, stream>>>(x, relax, F);
    pass2_combine<NC><<<(BG * 16) / 256, 256, 0, stream>>>(F, Mp);
    pass3_outputs<NC><<<threads13 / 256, 256, 0, stream>>>(x, relax, F, out);
}

extern "C" void kernel_launch(void* const* d_in, const int* in_sizes, int n_in,
                              void* d_out, int out_size, void* d_ws, size_t ws_size,
                              hipStream_t stream) {
    const float* x     = (const float*)d_in[0];   // [B,S,G] f32
    const float* relax = (const float*)d_in[1];   // [G] f32
    float* out = (float*)d_out;                   // [B,S,G,K] f32

    float* Mp = (float*)d_ws;                     // G*K*K floats
    float* F  = (float*)((char*)d_ws + 4096);     // BF*NC*24 floats

    const size_t need128 = 4096 + (size_t)BF * 128 * (GF * KF) * sizeof(float); // ~25 MB
    if (ws_size >= need128) {
        run_all<128>(x, relax, out, Mp, F, stream);
    } else {
        run_all<64>(x, relax, out, Mp, F, stream);
    }
}

// Round 6
// 488.205 us; speedup vs baseline: 1.2882x; 1.0953x over previous
//
#include <hip/hip_runtime.h>

// Laguerre FilterbankCell via chunked parallel linear scan.
// pass3: 4-step LDS staging per wave (chunk-run = 384 B = 3 full 128-B lines),
// packed cooperative flush -> every 128-B output line is written entirely by a
// single 1-KB store instruction. XOR swizzle (chunk&7)<<4 kills LDS bank
// conflicts on the row-major [64][96]f staging image.

#define KF 12
#define GF 2
#define BF 2048
#define SF 2048
#define BG (BF * GF)

// ---------------------------------------------------------------------------
__device__ __forceinline__ void fb_step2(float* __restrict__ y0, float* __restrict__ y1,
                                         float x0, float x1,
                                         float sa0, float tsb0, float sa1, float tsb1) {
    float pm0 = y0[0], pm1 = y1[0];
    y0[0] = fmaf(sa0, y0[0], tsb0 * x0);
    y1[0] = fmaf(sa1, y1[0], tsb1 * x1);
    #pragma unroll
    for (int j = 1; j < KF; ++j) {
        const float t0 = y0[j], t1 = y1[j];
        y0[j] = fmaf(sa0, t0, fmaf(sa0, y0[j - 1], -pm0));
        y1[j] = fmaf(sa1, t1, fmaf(sa1, y1[j - 1], -pm1));
        pm0 = t0; pm1 = t1;
    }
}

// ---------------------------------------------------------------------------
// Setup: Mp[g] = M^(SF/NC) via repeated squaring in LDS.
// ---------------------------------------------------------------------------
template <int NC>
__global__ void setup_mpow(const float* __restrict__ relax, float* __restrict__ Mp) {
    constexpr int LCH = SF / NC;
    constexpr int LOG2L = (LCH == 16) ? 4 : ((LCH == 32) ? 5 : 6);
    const int g = blockIdx.x;
    const int t = threadIdx.x;
    __shared__ float A[KF][KF];
    const float rx = relax[g];
    const float sa = sqrtf(rx);

    if (t < KF * KF) {
        const int j = t / KF, m = t % KF;
        float v = 0.0f;
        if (m == j) {
            v = sa;
        } else if (m < j) {
            float p = 1.0f;
            for (int i = 0; i < j - m - 1; ++i) p *= sa;
            v = -(1.0f - rx) * p;
        }
        A[j][m] = v;
    }
    __syncthreads();

    for (int it = 0; it < LOG2L; ++it) {
        float s = 0.0f;
        if (t < KF * KF) {
            const int j = t / KF, m = t % KF;
            #pragma unroll
            for (int i = 0; i < KF; ++i) s += A[j][i] * A[i][m];
        }
        __syncthreads();
        if (t < KF * KF) A[t / KF][t % KF] = s;
        __syncthreads();
    }

    if (t < KF * KF) Mp[g * KF * KF + t] = A[t / KF][t % KF];
}

// ---------------------------------------------------------------------------
// Pass 1: thread (b,c) runs chunk c from zero; stores 24-float end state at
// F[(b*NC + c)*24].
// ---------------------------------------------------------------------------
template <int NC>
__global__ __launch_bounds__(256, 4) void pass1_chunk_states(
        const float* __restrict__ x, const float* __restrict__ relax,
        float* __restrict__ F) {
    constexpr int LCH = SF / NC;
    const int tid = blockIdx.x * 256 + threadIdx.x;
    const int c = tid & (NC - 1);
    const int b = tid / NC;

    const float r0 = relax[0], r1 = relax[1];
    const float sa0 = sqrtf(r0), tsb0 = sqrtf(1.0f - r0);
    const float sa1 = sqrtf(r1), tsb1 = sqrtf(1.0f - r1);

    float y0[KF], y1[KF];
    #pragma unroll
    for (int k = 0; k < KF; ++k) { y0[k] = 0.0f; y1[k] = 0.0f; }

    const float4* xp = (const float4*)(x + ((size_t)b * SF + (size_t)c * LCH) * GF);
    for (int t2 = 0; t2 < LCH / 2; ++t2) {
        const float4 xv = xp[t2];
        fb_step2(y0, y1, xv.x, xv.y, sa0, tsb0, sa1, tsb1);
        fb_step2(y0, y1, xv.z, xv.w, sa0, tsb0, sa1, tsb1);
    }

    float4* Fp = (float4*)(F + ((size_t)b * NC + c) * (GF * KF));
    Fp[0] = make_float4(y0[0], y0[1], y0[2],  y0[3]);
    Fp[1] = make_float4(y0[4], y0[5], y0[6],  y0[7]);
    Fp[2] = make_float4(y0[8], y0[9], y0[10], y0[11]);
    Fp[3] = make_float4(y1[0], y1[1], y1[2],  y1[3]);
    Fp[4] = make_float4(y1[4], y1[5], y1[6],  y1[7]);
    Fp[5] = make_float4(y1[8], y1[9], y1[10], y1[11]);
}

// ---------------------------------------------------------------------------
// Pass 2: per (b,g): s_in(c) = Mp*s_in(c-1) + F(c-1), stored into slot c-1.
// ---------------------------------------------------------------------------
template <int NC>
__global__ void pass2_combine(float* __restrict__ F, const float* __restrict__ Mp) {
    const int tid = blockIdx.x * blockDim.x + threadIdx.x;   // BG*16 threads
    const int sub = tid & 15;
    const int bg  = tid >> 4;          // b*2+g
    const int b   = bg >> 1;
    const int g   = bg & 1;
    const int lane = threadIdx.x & 63;
    const int grpbase = lane & ~15;

    const int k = (sub < KF) ? sub : 0;
    float Mrow[KF];
    const float* mr = Mp + ((size_t)g * KF + k) * KF;
    #pragma unroll
    for (int m = 0; m < KF; ++m) Mrow[m] = mr[m];

    float* Fb = F + ((size_t)b * NC) * (GF * KF) + g * KF + k;

    float r = 0.0f;
    float fnext = Fb[0];
    for (int c = 1; c < NC; ++c) {
        const float fcur = fnext;
        if (c + 1 < NC) fnext = Fb[(size_t)c * (GF * KF)];
        float acc = fcur;
        #pragma unroll
        for (int m = 0; m < KF; ++m) {
            acc += Mrow[m] * __shfl(r, grpbase + m, 64);
        }
        if (sub < KF) Fb[(size_t)(c - 1) * (GF * KF)] = acc;
        r = acc;
    }
}

// ---------------------------------------------------------------------------
// Pass 3 staging helper: write one step's 24 floats into the swizzled image.
// ---------------------------------------------------------------------------
__device__ __forceinline__ void stage24(char* Lw, int kbase, int sswz,
                                        const float* __restrict__ y0,
                                        const float* __restrict__ y1) {
    *(float4*)(Lw + ((kbase +  0) ^ sswz)) = make_float4(y0[0], y0[1], y0[2],  y0[3]);
    *(float4*)(Lw + ((kbase + 16) ^ sswz)) = make_float4(y0[4], y0[5], y0[6],  y0[7]);
    *(float4*)(Lw + ((kbase + 32) ^ sswz)) = make_float4(y0[8], y0[9], y0[10], y0[11]);
    *(float4*)(Lw + ((kbase + 48) ^ sswz)) = make_float4(y1[0], y1[1], y1[2],  y1[3]);
    *(float4*)(Lw + ((kbase + 64) ^ sswz)) = make_float4(y1[4], y1[5], y1[6],  y1[7]);
    *(float4*)(Lw + ((kbase + 80) ^ sswz)) = make_float4(y1[8], y1[9], y1[10], y1[11]);
}

// ---------------------------------------------------------------------------
// Pass 3: wave owns 64 consecutive chunks of one b. Per 4-step window:
// stage [64 chunks][4 steps][24 floats] (XOR-swizzled), then flush packed:
// v = j*64+lane -> (chunk v/24, float4 v%24). Every 128-B line fully written
// by one instruction. Wave-private LDS -> no barriers.
// ---------------------------------------------------------------------------
template <int NC>
__global__ __launch_bounds__(128) void pass3_outputs(
        const float* __restrict__ x, const float* __restrict__ relax,
        const float* __restrict__ F, float* __restrict__ out) {
    constexpr int LCH   = SF / NC;      // steps per chunk
    constexpr int WPB   = NC / 64;      // waves per b
    constexpr int NWIN  = LCH / 4;      // 4-step windows per chunk
    constexpr int ROWF4 = LCH * 6;      // float4s per chunk output row
    __shared__ __align__(16) float lds[2 * 64 * 96];   // 48 KB

    const int lane = threadIdx.x & 63;
    const int w    = threadIdx.x >> 6;
    const int W    = blockIdx.x * 2 + w;
    const int b    = W / WPB;
    const int c0   = (W % WPB) * 64;
    const int c    = c0 + lane;

    const float r0 = relax[0], r1 = relax[1];
    const float sa0 = sqrtf(r0), tsb0 = sqrtf(1.0f - r0);
    const float sa1 = sqrtf(r1), tsb1 = sqrtf(1.0f - r1);

    float y0[KF], y1[KF];
    if (c == 0) {
        #pragma unroll
        for (int k = 0; k < KF; ++k) { y0[k] = 0.0f; y1[k] = 0.0f; }
    } else {
        const float4* Fp = (const float4*)(F + ((size_t)b * NC + (c - 1)) * (GF * KF));
        const float4 a0 = Fp[0], a1 = Fp[1], a2 = Fp[2];
        const float4 a3 = Fp[3], a4 = Fp[4], a5 = Fp[5];
        y0[0] = a0.x; y0[1] = a0.y; y0[2]  = a0.z; y0[3]  = a0.w;
        y0[4] = a1.x; y0[5] = a1.y; y0[6]  = a1.z; y0[7]  = a1.w;
        y0[8] = a2.x; y0[9] = a2.y; y0[10] = a2.z; y0[11] = a2.w;
        y1[0] = a3.x; y1[1] = a3.y; y1[2]  = a3.z; y1[3]  = a3.w;
        y1[4] = a4.x; y1[5] = a4.y; y1[6]  = a4.z; y1[7]  = a4.w;
        y1[8] = a5.x; y1[9] = a5.y; y1[10] = a5.z; y1[11] = a5.w;
    }

    char* Lw = (char*)&lds[w * 64 * 96];
    const int sbase = lane * 384;          // my chunk's row (384 B)
    const int sswz  = (lane & 7) << 4;

    // Flush tables (compile-time j -> registers; rule #20 safe).
    int gof[24], lof[24];
    #pragma unroll
    for (int j = 0; j < 24; ++j) {
        const int v  = j * 64 + lane;
        const int cf = v / 24;
        const int qf = v - cf * 24;
        gof[j] = (c0 + cf) * ROWF4 + qf;                    // float4 units
        lof[j] = (cf * 384 + qf * 16) ^ ((cf & 7) << 4);    // bytes
    }

    const float4* xp = (const float4*)(x + ((size_t)b * SF + (size_t)c * LCH) * GF);
    float4* outb = (float4*)(out + (size_t)b * SF * (GF * KF));

    for (int win = 0; win < NWIN; ++win) {
        const float4 xa = xp[2 * win];
        const float4 xb = xp[2 * win + 1];

        fb_step2(y0, y1, xa.x, xa.y, sa0, tsb0, sa1, tsb1);
        stage24(Lw, sbase +   0, sswz, y0, y1);
        fb_step2(y0, y1, xa.z, xa.w, sa0, tsb0, sa1, tsb1);
        stage24(Lw, sbase +  96, sswz, y0, y1);
        fb_step2(y0, y1, xb.x, xb.y, sa0, tsb0, sa1, tsb1);
        stage24(Lw, sbase + 192, sswz, y0, y1);
        fb_step2(y0, y1, xb.z, xb.w, sa0, tsb0, sa1, tsb1);
        stage24(Lw, sbase + 288, sswz, y0, y1);

        // Cooperative flush: 24 x 1-KB contiguous-line stores per wave.
        // Wave-private LDS; DS ops are in-order within a wave -> no barrier.
        const int tof = win * 24;          // t0*6 float4s
        #pragma unroll
        for (int j = 0; j < 24; ++j) {
            outb[(size_t)(gof[j] + tof)] = *(const float4*)(Lw + lof[j]);
        }
    }
}

// ---------------------------------------------------------------------------
template <int NC>
static void run_all(const float* x, const float* relax, float* out,
                    float* Mp, float* F, hipStream_t stream) {
    setup_mpow<NC><<<GF, 192, 0, stream>>>(relax, Mp);
    pass1_chunk_states<NC><<<(BF * NC) / 256, 256, 0, stream>>>(x, relax, F);
    pass2_combine<NC><<<(BG * 16) / 256, 256, 0, stream>>>(F, Mp);
    pass3_outputs<NC><<<(BF * (NC / 64)) / 2, 128, 0, stream>>>(x, relax, F, out);
}

extern "C" void kernel_launch(void* const* d_in, const int* in_sizes, int n_in,
                              void* d_out, int out_size, void* d_ws, size_t ws_size,
                              hipStream_t stream) {
    const float* x     = (const float*)d_in[0];   // [B,S,G] f32
    const float* relax = (const float*)d_in[1];   // [G] f32
    float* out = (float*)d_out;                   // [B,S,G,K] f32

    float* Mp = (float*)d_ws;                     // G*K*K floats
    float* F  = (float*)((char*)d_ws + 4096);     // BF*NC*24 floats

    const size_t need128 = 4096 + (size_t)BF * 128 * (GF * KF) * sizeof(float); // ~25 MB
    if (ws_size >= need128) {
        run_all<128>(x, relax, out, Mp, F, stream);
    } else {
        run_all<64>(x, relax, out, Mp, F, stream);
    }
}

// Round 7
// 479.351 us; speedup vs baseline: 1.3120x; 1.0185x over previous
//
#include <hip/hip_runtime.h>

// Laguerre FilterbankCell via chunked parallel linear scan.
// R7 changes: pass3 -> 64-thr/24KB blocks, window loop unrolled x2 (2-deep
// store pipeline, partial vmcnt waits), nontemporal output stores (no L2
// allocate/churn). setup folded into pass2; pass2 gets 3-deep prefetch.

#define KF 12
#define GF 2
#define BF 2048
#define SF 2048
#define BG (BF * GF)

typedef float f32x4 __attribute__((ext_vector_type(4)));

// ---------------------------------------------------------------------------
__device__ __forceinline__ void fb_step2(float* __restrict__ y0, float* __restrict__ y1,
                                         float x0, float x1,
                                         float sa0, float tsb0, float sa1, float tsb1) {
    float pm0 = y0[0], pm1 = y1[0];
    y0[0] = fmaf(sa0, y0[0], tsb0 * x0);
    y1[0] = fmaf(sa1, y1[0], tsb1 * x1);
    #pragma unroll
    for (int j = 1; j < KF; ++j) {
        const float t0 = y0[j], t1 = y1[j];
        y0[j] = fmaf(sa0, t0, fmaf(sa0, y0[j - 1], -pm0));
        y1[j] = fmaf(sa1, t1, fmaf(sa1, y1[j - 1], -pm1));
        pm0 = t0; pm1 = t1;
    }
}

// ---------------------------------------------------------------------------
// Pass 1: thread (b,c) runs chunk c from zero; stores 24-float end state at
// F[(b*NC + c)*24].
// ---------------------------------------------------------------------------
template <int NC>
__global__ __launch_bounds__(256, 4) void pass1_chunk_states(
        const float* __restrict__ x, const float* __restrict__ relax,
        float* __restrict__ F) {
    constexpr int LCH = SF / NC;
    const int tid = blockIdx.x * 256 + threadIdx.x;
    const int c = tid & (NC - 1);
    const int b = tid / NC;

    const float r0 = relax[0], r1 = relax[1];
    const float sa0 = sqrtf(r0), tsb0 = sqrtf(1.0f - r0);
    const float sa1 = sqrtf(r1), tsb1 = sqrtf(1.0f - r1);

    float y0[KF], y1[KF];
    #pragma unroll
    for (int k = 0; k < KF; ++k) { y0[k] = 0.0f; y1[k] = 0.0f; }

    const float4* xp = (const float4*)(x + ((size_t)b * SF + (size_t)c * LCH) * GF);
    for (int t2 = 0; t2 < LCH / 2; ++t2) {
        const float4 xv = xp[t2];
        fb_step2(y0, y1, xv.x, xv.y, sa0, tsb0, sa1, tsb1);
        fb_step2(y0, y1, xv.z, xv.w, sa0, tsb0, sa1, tsb1);
    }

    float4* Fp = (float4*)(F + ((size_t)b * NC + c) * (GF * KF));
    Fp[0] = make_float4(y0[0], y0[1], y0[2],  y0[3]);
    Fp[1] = make_float4(y0[4], y0[5], y0[6],  y0[7]);
    Fp[2] = make_float4(y0[8], y0[9], y0[10], y0[11]);
    Fp[3] = make_float4(y1[0], y1[1], y1[2],  y1[3]);
    Fp[4] = make_float4(y1[4], y1[5], y1[6],  y1[7]);
    Fp[5] = make_float4(y1[8], y1[9], y1[10], y1[11]);
}

// ---------------------------------------------------------------------------
// Pass 2 (setup fused): build M^(SF/NC) in LDS (repeated squaring), then per
// (b,g): s_in(c) = Mp*s_in(c-1) + F(c-1), stored into slot c-1. 16 lanes per
// (b,g); 3-deep rolling prefetch hides L3 latency of the F loads.
// ---------------------------------------------------------------------------
template <int NC>
__global__ __launch_bounds__(256) void pass2_combine(
        float* __restrict__ F, const float* __restrict__ relax) {
    constexpr int LCH = SF / NC;
    constexpr int LOG2L = (LCH == 16) ? 4 : ((LCH == 32) ? 5 : 6);
    __shared__ float A[GF][KF][KF];
    __shared__ float Btmp[GF][KF][KF];

    for (int e = threadIdx.x; e < GF * KF * KF; e += 256) {
        const int g = e / (KF * KF);
        const int t = e % (KF * KF);
        const int j = t / KF, m = t % KF;
        const float rx = relax[g];
        const float sa = sqrtf(rx);
        float v = 0.0f;
        if (m == j) {
            v = sa;
        } else if (m < j) {
            float p = 1.0f;
            for (int i = 0; i < j - m - 1; ++i) p *= sa;
            v = -(1.0f - rx) * p;
        }
        A[g][j][m] = v;
    }
    __syncthreads();

    for (int it = 0; it < LOG2L; ++it) {
        for (int e = threadIdx.x; e < GF * KF * KF; e += 256) {
            const int g = e / (KF * KF);
            const int t = e % (KF * KF);
            const int j = t / KF, m = t % KF;
            float s = 0.0f;
            #pragma unroll
            for (int i = 0; i < KF; ++i) s += A[g][j][i] * A[g][i][m];
            Btmp[g][j][m] = s;
        }
        __syncthreads();
        for (int e = threadIdx.x; e < GF * KF * KF; e += 256) {
            const int g = e / (KF * KF);
            const int t = e % (KF * KF);
            A[g][t / KF][t % KF] = Btmp[g][t / KF][t % KF];
        }
        __syncthreads();
    }

    const int tid = blockIdx.x * 256 + threadIdx.x;   // BG*16 threads
    const int sub = tid & 15;
    const int bg  = tid >> 4;          // b*2+g
    const int b   = bg >> 1;
    const int g   = bg & 1;
    const int lane = threadIdx.x & 63;
    const int grpbase = lane & ~15;

    const int k = (sub < KF) ? sub : 0;
    float Mrow[KF];
    #pragma unroll
    for (int m = 0; m < KF; ++m) Mrow[m] = A[g][k][m];

    float* Fb = F + ((size_t)b * NC) * (GF * KF) + g * KF + k;

    float r = 0.0f;
    float f0 = Fb[0];                         // slot 0
    float f1 = Fb[GF * KF];                   // slot 1
    float f2 = Fb[2 * (GF * KF)];             // slot 2
    for (int c = 1; c < NC; ++c) {
        float acc = f0;
        f0 = f1; f1 = f2;
        if (c + 4 <= NC) f2 = Fb[(size_t)(c + 2) * (GF * KF)];
        #pragma unroll
        for (int m = 0; m < KF; ++m) {
            acc += Mrow[m] * __shfl(r, grpbase + m, 64);
        }
        if (sub < KF) Fb[(size_t)(c - 1) * (GF * KF)] = acc;
        r = acc;
    }
}

// ---------------------------------------------------------------------------
// Pass 3 staging helper: write one step's 24 floats into the swizzled image.
// ---------------------------------------------------------------------------
__device__ __forceinline__ void stage24(char* Lw, int kbase, int sswz,
                                        const float* __restrict__ y0,
                                        const float* __restrict__ y1) {
    *(float4*)(Lw + ((kbase +  0) ^ sswz)) = make_float4(y0[0], y0[1], y0[2],  y0[3]);
    *(float4*)(Lw + ((kbase + 16) ^ sswz)) = make_float4(y0[4], y0[5], y0[6],  y0[7]);
    *(float4*)(Lw + ((kbase + 32) ^ sswz)) = make_float4(y0[8], y0[9], y0[10], y0[11]);
    *(float4*)(Lw + ((kbase + 48) ^ sswz)) = make_float4(y1[0], y1[1], y1[2],  y1[3]);
    *(float4*)(Lw + ((kbase + 64) ^ sswz)) = make_float4(y1[4], y1[5], y1[6],  y1[7]);
    *(float4*)(Lw + ((kbase + 80) ^ sswz)) = make_float4(y1[8], y1[9], y1[10], y1[11]);
}

// ---------------------------------------------------------------------------
// Pass 3: one wave per block (24 KB LDS -> 6 blocks/CU). Wave owns 64
// consecutive chunks of one b. Per 4-step window: stage [64][4][24]f
// (XOR-swizzled), flush packed v=j*64+lane -> (chunk v/24, f4 v%24): every
// 128-B line written entirely by one instruction. Nontemporal stores (no L2
// allocate). Window loop unrolled x2 -> 2-deep store pipeline (partial vmcnt
// waits instead of full drain). Wave-private LDS -> no barriers.
// ---------------------------------------------------------------------------
template <int NC>
__global__ __launch_bounds__(64) void pass3_outputs(
        const float* __restrict__ x, const float* __restrict__ relax,
        const float* __restrict__ F, float* __restrict__ out) {
    constexpr int LCH   = SF / NC;      // steps per chunk
    constexpr int WPB   = NC / 64;      // waves per b
    constexpr int NWIN  = LCH / 4;      // 4-step windows per chunk
    constexpr int ROWF4 = LCH * 6;      // float4s per chunk output row
    __shared__ __align__(16) float lds[64 * 96];   // 24 KB

    const int lane = threadIdx.x;
    const int W    = blockIdx.x;
    const int b    = W / WPB;
    const int c0   = (W % WPB) * 64;
    const int c    = c0 + lane;

    const float r0 = relax[0], r1 = relax[1];
    const float sa0 = sqrtf(r0), tsb0 = sqrtf(1.0f - r0);
    const float sa1 = sqrtf(r1), tsb1 = sqrtf(1.0f - r1);

    float y0[KF], y1[KF];
    if (c == 0) {
        #pragma unroll
        for (int k = 0; k < KF; ++k) { y0[k] = 0.0f; y1[k] = 0.0f; }
    } else {
        const float4* Fp = (const float4*)(F + ((size_t)b * NC + (c - 1)) * (GF * KF));
        const float4 a0 = Fp[0], a1 = Fp[1], a2 = Fp[2];
        const float4 a3 = Fp[3], a4 = Fp[4], a5 = Fp[5];
        y0[0] = a0.x; y0[1] = a0.y; y0[2]  = a0.z; y0[3]  = a0.w;
        y0[4] = a1.x; y0[5] = a1.y; y0[6]  = a1.z; y0[7]  = a1.w;
        y0[8] = a2.x; y0[9] = a2.y; y0[10] = a2.z; y0[11] = a2.w;
        y1[0] = a3.x; y1[1] = a3.y; y1[2]  = a3.z; y1[3]  = a3.w;
        y1[4] = a4.x; y1[5] = a4.y; y1[6]  = a4.z; y1[7]  = a4.w;
        y1[8] = a5.x; y1[9] = a5.y; y1[10] = a5.z; y1[11] = a5.w;
    }

    char* Lw = (char*)lds;
    const int sbase = lane * 384;          // my chunk's row (384 B)
    const int sswz  = (lane & 7) << 4;

    // Flush tables (compile-time j -> registers).
    int gof[24], lof[24];
    #pragma unroll
    for (int j = 0; j < 24; ++j) {
        const int v  = j * 64 + lane;
        const int cf = v / 24;
        const int qf = v - cf * 24;
        gof[j] = (c0 + cf) * ROWF4 + qf;                    // float4 units
        lof[j] = (cf * 384 + qf * 16) ^ ((cf & 7) << 4);    // bytes
    }

    const float4* xp = (const float4*)(x + ((size_t)b * SF + (size_t)c * LCH) * GF);
    f32x4* outb = (f32x4*)(out + (size_t)b * SF * (GF * KF));

    #pragma unroll 2
    for (int win = 0; win < NWIN; ++win) {
        const float4 xa = xp[2 * win];
        const float4 xb = xp[2 * win + 1];

        fb_step2(y0, y1, xa.x, xa.y, sa0, tsb0, sa1, tsb1);
        stage24(Lw, sbase +   0, sswz, y0, y1);
        fb_step2(y0, y1, xa.z, xa.w, sa0, tsb0, sa1, tsb1);
        stage24(Lw, sbase +  96, sswz, y0, y1);
        fb_step2(y0, y1, xb.x, xb.y, sa0, tsb0, sa1, tsb1);
        stage24(Lw, sbase + 192, sswz, y0, y1);
        fb_step2(y0, y1, xb.z, xb.w, sa0, tsb0, sa1, tsb1);
        stage24(Lw, sbase + 288, sswz, y0, y1);

        // Cooperative flush: 24 x 1-KB contiguous-line nontemporal stores.
        // Wave-private LDS; DS ops in-order within a wave -> no barrier.
        const int tof = win * 24;          // t0*6 float4s
        #pragma unroll
        for (int j = 0; j < 24; ++j) {
            const f32x4 v = *(const f32x4*)(Lw + lof[j]);
            __builtin_nontemporal_store(v, &outb[(size_t)(gof[j] + tof)]);
        }
    }
}

// ---------------------------------------------------------------------------
template <int NC>
static void run_all(const float* x, const float* relax, float* out,
                    float* F, hipStream_t stream) {
    pass1_chunk_states<NC><<<(BF * NC) / 256, 256, 0, stream>>>(x, relax, F);
    pass2_combine<NC><<<(BG * 16) / 256, 256, 0, stream>>>(F, relax);
    pass3_outputs<NC><<<BF * (NC / 64), 64, 0, stream>>>(x, relax, F, out);
}

extern "C" void kernel_launch(void* const* d_in, const int* in_sizes, int n_in,
                              void* d_out, int out_size, void* d_ws, size_t ws_size,
                              hipStream_t stream) {
    const float* x     = (const float*)d_in[0];   // [B,S,G] f32
    const float* relax = (const float*)d_in[1];   // [G] f32
    float* out = (float*)d_out;                   // [B,S,G,K] f32

    float* F = (float*)d_ws;                      // BF*NC*24 floats

    const size_t need128 = (size_t)BF * 128 * (GF * KF) * sizeof(float); // ~25 MB
    if (ws_size >= need128) {
        run_all<128>(x, relax, out, F, stream);
    } else {
        run_all<64>(x, relax, out, F, stream);
    }
}